// Round 5
// baseline (1447.797 us; speedup 1.0000x reference)
//
#include <hip/hip_runtime.h>
#include <hip/hip_bf16.h>
#include <stdint.h>

typedef __bf16 bf16_t;
typedef bf16_t bf16x8 __attribute__((ext_vector_type(8)));
typedef float f32x4 __attribute__((ext_vector_type(4)));

#define N_NODES 10000
#define N_EDGES 160000
#define IN_DIM 128
#define HID 512
#define LN_EPS 1e-5f

#define AS1 __attribute__((address_space(1)))
#define AS3 __attribute__((address_space(3)))

static __device__ __forceinline__ void gload_lds16(const void* g, void* l) {
  __builtin_amdgcn_global_load_lds((const AS1 void*)g, (AS3 void*)l, 16, 0, 0);
}

// ---------------- small utility kernels ----------------

__global__ void k_cast(const float* __restrict__ s, bf16_t* __restrict__ d, int n) {
  int i = blockIdx.x * 256 + threadIdx.x;
  if (i < n) d[i] = (bf16_t)s[i];
}

// LDS-tiled transpose+cast: dst[N][K] = bf16(src[K][N]); grid (N/32, K/32), 256 thr
__global__ __launch_bounds__(256) void k_tpose(const float* __restrict__ src,
                                               bf16_t* __restrict__ dst, int K, int N) {
  __shared__ float t[32][33];
  int cx = threadIdx.x & 31, ry = threadIdx.x >> 5;  // 0..31, 0..7
  int n0 = blockIdx.x * 32, k0 = blockIdx.y * 32;
#pragma unroll
  for (int i = 0; i < 32; i += 8)
    t[ry + i][cx] = src[(size_t)(k0 + ry + i) * N + n0 + cx];
  __syncthreads();
#pragma unroll
  for (int i = 0; i < 32; i += 8)
    dst[(size_t)(n0 + ry + i) * K + k0 + cx] = (bf16_t)t[cx][ry + i];
}

__global__ void k_deg_init(float* deg) {
  int i = blockIdx.x * 256 + threadIdx.x;
  if (i < N_NODES) deg[i] = 1.0f;  // self-loop
}
__global__ void k_deg_count(const int* __restrict__ col, float* deg) {
  int e = blockIdx.x * 256 + threadIdx.x;
  if (e < N_EDGES) atomicAdd(&deg[col[e]], 1.0f);
}
__global__ void k_dis(const float* __restrict__ deg, float* __restrict__ dis) {
  int i = blockIdx.x * 256 + threadIdx.x;
  if (i < N_NODES) dis[i] = rsqrtf(deg[i]);  // deg >= 1 always
}

// ---------------- CSR build (edges sorted by target) ----------------

__global__ void k_zero2(int* a, int* b) {
  int i = blockIdx.x * 256 + threadIdx.x;
  if (i < N_NODES) { a[i] = 0; b[i] = 0; }
}
__global__ void k_cnt(const int* __restrict__ col, int* cnt) {
  int e = blockIdx.x * 256 + threadIdx.x;
  if (e < N_EDGES) atomicAdd(&cnt[col[e]], 1);
}
// single-block exclusive scan: rowptr[0..N_NODES]
__global__ __launch_bounds__(256) void k_scan(const int* __restrict__ cnt,
                                              int* __restrict__ rowptr) {
  __shared__ int part[256];
  __shared__ int pref[257];
  int tid = threadIdx.x;
  const int CH = 40;  // 256*40 >= 10001
  int s = 0;
  for (int i = 0; i < CH; ++i) {
    int idx = tid * CH + i;
    if (idx < N_NODES) s += cnt[idx];
  }
  part[tid] = s;
  __syncthreads();
  if (tid == 0) {
    int a = 0;
    for (int i = 0; i < 256; ++i) { pref[i] = a; a += part[i]; }
    pref[256] = a;
  }
  __syncthreads();
  int a = pref[tid];
  for (int i = 0; i < CH; ++i) {
    int idx = tid * CH + i;
    if (idx < N_NODES) {
      rowptr[idx] = a;
      a += cnt[idx];
    } else if (idx == N_NODES) {
      rowptr[idx] = a;
    }
  }
}
__global__ void k_fill(const int* __restrict__ ei, const float* __restrict__ dis,
                       const int* __restrict__ rowptr, int* __restrict__ cursor,
                       int* __restrict__ esrc, float* __restrict__ ew) {
  int e = blockIdx.x * 256 + threadIdx.x;
  if (e >= N_EDGES) return;
  int s = ei[e];
  int t = ei[N_EDGES + e];
  int pos = atomicAdd(&cursor[t], 1);
  int o = rowptr[t] + pos;
  esrc[o] = s;
  ew[o] = dis[s] * dis[t];
}

// ---------------- fused aggregation + ReLU + LayerNorm (T in bf16) ----------------
__global__ __launch_bounds__(256) void k_agg_ln(
    const bf16_t* __restrict__ T, const int* __restrict__ rowptr,
    const int* __restrict__ esrc, const float* __restrict__ ew,
    const float* __restrict__ dis, const float* __restrict__ bias,
    const float* __restrict__ g, const float* __restrict__ b,
    bf16_t* __restrict__ out) {
  int w = threadIdx.x >> 6, lane = threadIdx.x & 63;
  int node = blockIdx.x * 4 + w;
  if (node >= N_NODES) return;
  int d0 = lane << 3;  // 8 dims per lane
  float dw = dis[node];
  dw *= dw;
  float a[8];
  {
    bf16x8 tn = *(const bf16x8*)(T + (size_t)node * HID + d0);
    const f32x4* bi = (const f32x4*)(bias + d0);
    f32x4 bv0 = bi[0], bv1 = bi[1];
#pragma unroll
    for (int j = 0; j < 4; ++j) a[j] = dw * (float)tn[j] + bv0[j];
#pragma unroll
    for (int j = 0; j < 4; ++j) a[4 + j] = dw * (float)tn[4 + j] + bv1[j];
  }
  int e = rowptr[node], e1 = rowptr[node + 1];
  for (; e + 1 < e1; e += 2) {
    int s0 = esrc[e], s1i = esrc[e + 1];
    float w0 = ew[e], w1 = ew[e + 1];
    bf16x8 t0 = *(const bf16x8*)(T + (size_t)s0 * HID + d0);
    bf16x8 t1 = *(const bf16x8*)(T + (size_t)s1i * HID + d0);
#pragma unroll
    for (int j = 0; j < 8; ++j) a[j] += w0 * (float)t0[j] + w1 * (float)t1[j];
  }
  if (e < e1) {
    int s0 = esrc[e];
    float w0 = ew[e];
    bf16x8 t0 = *(const bf16x8*)(T + (size_t)s0 * HID + d0);
#pragma unroll
    for (int j = 0; j < 8; ++j) a[j] += w0 * (float)t0[j];
  }
  float s1 = 0.f, s2 = 0.f;
#pragma unroll
  for (int j = 0; j < 8; ++j) {
    a[j] = fmaxf(a[j], 0.f);
    s1 += a[j];
    s2 += a[j] * a[j];
  }
#pragma unroll
  for (int off = 32; off > 0; off >>= 1) {
    s1 += __shfl_xor(s1, off);
    s2 += __shfl_xor(s2, off);
  }
  const float invD = 1.0f / (float)HID;
  float mean = s1 * invD;
  float var = s2 * invD - mean * mean;
  float inv = rsqrtf(var + LN_EPS);
  bf16_t ob[8];
#pragma unroll
  for (int j = 0; j < 8; ++j) {
    int d = d0 + j;
    ob[j] = (bf16_t)((a[j] - mean) * inv * g[d] + b[d]);
  }
  *(bf16x8*)(out + (size_t)node * HID + d0) = *(bf16x8*)ob;
}

// wave-per-row: z = relu(LN(z)) in place, D=1024, bf16
__global__ __launch_bounds__(256) void k_ln_relu_1024(
    bf16_t* __restrict__ z, const float* __restrict__ g,
    const float* __restrict__ b, int rows) {
  int w = threadIdx.x >> 6, lane = threadIdx.x & 63;
  int row = blockIdx.x * 4 + w;
  if (row >= rows) return;
  bf16_t* zp = z + (size_t)row * 1024 + (lane << 4);  // 16 elems/lane
  bf16x8 v0 = *(bf16x8*)zp;
  bf16x8 v1 = *(bf16x8*)(zp + 8);
  float f[16];
#pragma unroll
  for (int j = 0; j < 8; ++j) { f[j] = (float)v0[j]; f[8 + j] = (float)v1[j]; }
  float s1 = 0.f, s2 = 0.f;
#pragma unroll
  for (int j = 0; j < 16; ++j) { s1 += f[j]; s2 += f[j] * f[j]; }
#pragma unroll
  for (int off = 32; off > 0; off >>= 1) {
    s1 += __shfl_xor(s1, off);
    s2 += __shfl_xor(s2, off);
  }
  const float invD = 1.0f / 1024.0f;
  float mean = s1 * invD;
  float var = s2 * invD - mean * mean;
  float inv = rsqrtf(var + LN_EPS);
  int d0 = lane << 4;
  bf16_t o0[8], o1[8];
#pragma unroll
  for (int j = 0; j < 8; ++j) {
    o0[j] = (bf16_t)fmaxf((f[j] - mean) * inv * g[d0 + j] + b[d0 + j], 0.f);
    o1[j] = (bf16_t)fmaxf((f[8 + j] - mean) * inv * g[d0 + 8 + j] + b[d0 + 8 + j], 0.f);
  }
  *(bf16x8*)zp = *(bf16x8*)o0;
  *(bf16x8*)(zp + 8) = *(bf16x8*)o1;
}

// wave-per-row: out[row] = dot(relu(LN(z1[row])), mw2) + mb2, D=512, bf16 in
__global__ __launch_bounds__(256) void k_ln_dot(
    const bf16_t* __restrict__ z1, const float* __restrict__ g,
    const float* __restrict__ b, const float* __restrict__ mw2,
    const float* __restrict__ mb2, float* __restrict__ out, int rows) {
  int w = threadIdx.x >> 6, lane = threadIdx.x & 63;
  int row = blockIdx.x * 4 + w;
  if (row >= rows) return;
  int d0 = lane << 3;
  bf16x8 v = *(const bf16x8*)(z1 + (size_t)row * 512 + d0);
  float f[8];
#pragma unroll
  for (int j = 0; j < 8; ++j) f[j] = (float)v[j];
  float s1 = 0.f, s2 = 0.f;
#pragma unroll
  for (int j = 0; j < 8; ++j) { s1 += f[j]; s2 += f[j] * f[j]; }
#pragma unroll
  for (int off = 32; off > 0; off >>= 1) {
    s1 += __shfl_xor(s1, off);
    s2 += __shfl_xor(s2, off);
  }
  const float invD = 1.0f / 512.0f;
  float mean = s1 * invD;
  float var = s2 * invD - mean * mean;
  float inv = rsqrtf(var + LN_EPS);
  float acc = 0.f;
#pragma unroll
  for (int j = 0; j < 8; ++j) {
    float y = fmaxf((f[j] - mean) * inv * g[d0 + j] + b[d0 + j], 0.f);
    acc += y * mw2[d0 + j];
  }
#pragma unroll
  for (int off = 32; off > 0; off >>= 1) acc += __shfl_xor(acc, off);
  if (lane == 0) out[row] = acc + mb2[0];
}

// ---------------- GEMM (m97 structure + chunk swizzle + LDS double-buffer) ----
// LDS layout: row-major [row][32] bf16, but the 4 16B-chunks of each row are
// rotated by (row>>1)&3. Staging stays lane-contiguous in LDS (global_load_lds
// HW requirement); each lane instead fetches the rotated *global* k-chunk.
// Fragment reads at chunk (quad + row>>1)&3 then see 2-way bank aliasing (free)
// instead of 8-way.
#define BM 128
#define BN 128
#define BK 32

__global__ __launch_bounds__(256) void k_gemm(
    const bf16_t* __restrict__ A, const bf16_t* __restrict__ Hn,
    const int* __restrict__ srcI, const int* __restrict__ dstI,
    const bf16_t* __restrict__ Bt, const float* __restrict__ bias,
    bf16_t* __restrict__ C, int M, int N, int K, int gather) {
  __shared__ __align__(16) bf16_t sA[2 * BM * BK];
  __shared__ __align__(16) bf16_t sB[2 * BN * BK];

  int tid = threadIdx.x;
  int row0 = blockIdx.y * BM, col0 = blockIdx.x * BN;
  int lane = tid & 63, w = tid >> 6;
  int quad = lane >> 4, l15 = lane & 15;
  int wr = (w >> 1) << 6, wc = (w & 1) << 6;

  int r0l = tid >> 2, r1l = r0l + 64;            // tile rows staged by this thread
  int kchunk = ((tid & 3) - (tid >> 3)) & 3;     // rotated global k-chunk
  int ksegg = kchunk << 3;                       // global k element offset

  const bf16_t *pa0 = nullptr, *pa1 = nullptr;
  int aS0 = 0, aD0 = 0, aS1 = 0, aD1 = 0;
  if (gather) {
    aS0 = srcI[row0 + r0l]; aD0 = dstI[row0 + r0l];
    aS1 = srcI[row0 + r1l]; aD1 = dstI[row0 + r1l];
  } else {
    int g0 = row0 + r0l; if (g0 >= M) g0 = M - 1;  // clamp; never stored
    int g1 = row0 + r1l; if (g1 >= M) g1 = M - 1;
    pa0 = A + (size_t)g0 * K;
    pa1 = A + (size_t)g1 * K;
  }
  const bf16_t* pb0 = Bt + (size_t)(col0 + r0l) * K;
  const bf16_t* pb1 = Bt + (size_t)(col0 + r1l) * K;

  int ldsb = (tid & ~63) * 8;  // wave-uniform LDS element base

  auto stage = [&](int k0, int bsel) {
    int kk = k0 + ksegg;
    const bf16_t *ga0, *ga1;
    if (gather) {
      int off = kk & (HID - 1);
      ga0 = Hn + (size_t)(kk < HID ? aS0 : aD0) * HID + off;
      ga1 = Hn + (size_t)(kk < HID ? aS1 : aD1) * HID + off;
    } else {
      ga0 = pa0 + kk;
      ga1 = pa1 + kk;
    }
    bf16_t* dA = sA + (bsel << 12) + ldsb;
    bf16_t* dB = sB + (bsel << 12) + ldsb;
    gload_lds16(ga0, dA);
    gload_lds16(ga1, dA + 2048);
    gload_lds16(pb0 + kk, dB);
    gload_lds16(pb1 + kk, dB + 2048);
  };

  f32x4 acc[4][4] = {};

  stage(0, 0);
  int buf = 0;
  for (int k0 = 0; k0 < K; k0 += BK) {
    __syncthreads();  // drains vmcnt: current buf staged; prev reads done
    if (k0 + BK < K) stage(k0 + BK, buf ^ 1);  // async prefetch into other buf

    int bo = buf << 12;
    bf16x8 af[4], bfr[4];
#pragma unroll
    for (int i = 0; i < 4; ++i) {
      int rr = wr + (i << 4) + l15;
      af[i] = *(const bf16x8*)&sA[bo + rr * BK + ((((quad + (rr >> 1)) & 3)) << 3)];
    }
#pragma unroll
    for (int j = 0; j < 4; ++j) {
      int rr = wc + (j << 4) + l15;
      bfr[j] = *(const bf16x8*)&sB[bo + rr * BK + ((((quad + (rr >> 1)) & 3)) << 3)];
    }
#pragma unroll
    for (int i = 0; i < 4; ++i)
#pragma unroll
      for (int j = 0; j < 4; ++j)
        acc[i][j] = __builtin_amdgcn_mfma_f32_16x16x32_bf16(af[i], bfr[j], acc[i][j], 0, 0, 0);
    buf ^= 1;
  }

  // epilogue: C/D layout col=lane&15, row=quad*4+reg (verified m89/m91)
#pragma unroll
  for (int i = 0; i < 4; ++i) {
    int r0e = row0 + wr + (i << 4) + (quad << 2);
#pragma unroll
    for (int j = 0; j < 4; ++j) {
      int gc = col0 + wc + (j << 4) + l15;
      float bb = bias ? bias[gc] : 0.0f;
#pragma unroll
      for (int r2 = 0; r2 < 4; ++r2) {
        int gr = r0e + r2;
        if (gr < M) C[(size_t)gr * N + gc] = (bf16_t)(acc[i][j][r2] + bb);
      }
    }
  }
}

// ---------------- host launch ----------------

extern "C" void kernel_launch(void* const* d_in, const int* in_sizes, int n_in,
                              void* d_out, int out_size, void* d_ws, size_t ws_size,
                              hipStream_t stream) {
  const float* x = (const float*)d_in[0];
  const int* ei = (const int*)d_in[1];
  const float* w0 = (const float*)d_in[2];
  const float* b0 = (const float*)d_in[3];
  const float* wsL = (const float*)d_in[4];
  const float* bsL = (const float*)d_in[5];
  const float* ln_g = (const float*)d_in[6];
  const float* ln_b = (const float*)d_in[7];
  const float* mw0 = (const float*)d_in[8];
  const float* mb0 = (const float*)d_in[9];
  const float* mg0 = (const float*)d_in[10];
  const float* mbt0 = (const float*)d_in[11];
  const float* mw1 = (const float*)d_in[12];
  const float* mb1 = (const float*)d_in[13];
  const float* mg1 = (const float*)d_in[14];
  const float* mbt1 = (const float*)d_in[15];
  const float* mw2 = (const float*)d_in[16];
  const float* mb2 = (const float*)d_in[17];
  float* out = (float*)d_out;

  char* p = (char*)d_ws;
  auto alloc = [&](size_t bytes) -> void* {
    void* r = (void*)p;
    p += (bytes + 255) & ~(size_t)255;
    return r;
  };
  float* deg = (float*)alloc((size_t)N_NODES * 4);
  float* dis = (float*)alloc((size_t)N_NODES * 4);
  int* cnt = (int*)alloc((size_t)N_NODES * 4);
  int* cursor = (int*)alloc((size_t)N_NODES * 4);
  int* rowptr = (int*)alloc((size_t)(N_NODES + 1) * 4);
  int* esrc = (int*)alloc((size_t)N_EDGES * 4);
  float* ew = (float*)alloc((size_t)N_EDGES * 4);
  bf16_t* xb = (bf16_t*)alloc((size_t)N_NODES * IN_DIM * 2);
  bf16_t* hb0 = (bf16_t*)alloc((size_t)N_NODES * HID * 2);
  bf16_t* hb1 = (bf16_t*)alloc((size_t)N_NODES * HID * 2);
  bf16_t* w0t = (bf16_t*)alloc((size_t)HID * IN_DIM * 2);
  bf16_t* wst = (bf16_t*)alloc((size_t)3 * HID * HID * 2);
  bf16_t* mw0t = (bf16_t*)alloc((size_t)1024 * 1024 * 2);
  bf16_t* mw1t = (bf16_t*)alloc((size_t)512 * 1024 * 2);
  size_t fixed = (size_t)(p - (char*)d_ws);

  // overlap pool: GCN-phase T (bf16) vs MLP z0 (2048 B/edge) + z1 (1024 B/edge)
  int CE = 3200;
  const int ce_opts[4] = {160000, 80000, 32000, 16000};
  for (int i = 0; i < 4; ++i) {
    size_t pool_need = (size_t)ce_opts[i] * 3072;
    size_t tneed = (size_t)N_NODES * HID * 2;
    if (pool_need < tneed) pool_need = tneed;
    if (fixed + pool_need + 4096 <= ws_size) { CE = ce_opts[i]; break; }
  }
  char* pool = p;
  bf16_t* T = (bf16_t*)pool;
  bf16_t* z0 = (bf16_t*)pool;  // aliases T; GCN fully precedes MLP (same stream)
  bf16_t* z1 = (bf16_t*)(pool + (size_t)CE * 2048);

  k_cast<<<(N_NODES * IN_DIM + 255) / 256, 256, 0, stream>>>(x, xb, N_NODES * IN_DIM);
  { dim3 g(HID / 32, IN_DIM / 32);
    k_tpose<<<g, 256, 0, stream>>>(w0, w0t, IN_DIM, HID); }
  for (int i = 0; i < 3; ++i) {
    dim3 g(HID / 32, HID / 32);
    k_tpose<<<g, 256, 0, stream>>>(wsL + (size_t)i * HID * HID,
                                   wst + (size_t)i * HID * HID, HID, HID);
  }
  { dim3 g(1024 / 32, 1024 / 32);
    k_tpose<<<g, 256, 0, stream>>>(mw0, mw0t, 1024, 1024); }
  { dim3 g(512 / 32, 1024 / 32);
    k_tpose<<<g, 256, 0, stream>>>(mw1, mw1t, 1024, 512); }

  k_deg_init<<<(N_NODES + 255) / 256, 256, 0, stream>>>(deg);
  k_deg_count<<<(N_EDGES + 255) / 256, 256, 0, stream>>>(ei + N_EDGES, deg);
  k_dis<<<(N_NODES + 255) / 256, 256, 0, stream>>>(deg, dis);

  k_zero2<<<(N_NODES + 255) / 256, 256, 0, stream>>>(cnt, cursor);
  k_cnt<<<(N_EDGES + 255) / 256, 256, 0, stream>>>(ei + N_EDGES, cnt);
  k_scan<<<1, 256, 0, stream>>>(cnt, rowptr);
  k_fill<<<(N_EDGES + 255) / 256, 256, 0, stream>>>(ei, dis, rowptr, cursor, esrc, ew);

  bf16_t* hbufs[2] = {hb0, hb1};
  for (int L = 0; L < 4; ++L) {
    const bf16_t* Ain = (L == 0) ? xb : hbufs[(L + 1) & 1];
    int K = (L == 0) ? IN_DIM : HID;
    const bf16_t* Bt = (L == 0) ? w0t : wst + (size_t)(L - 1) * HID * HID;
    dim3 grid(HID / BN, (N_NODES + BM - 1) / BM);
    k_gemm<<<grid, 256, 0, stream>>>(Ain, nullptr, nullptr, nullptr, Bt, nullptr,
                                     T, N_NODES, HID, K, 0);
    const float* bias = (L == 0) ? b0 : bsL + (size_t)(L - 1) * HID;
    k_agg_ln<<<(N_NODES + 3) / 4, 256, 0, stream>>>(
        T, rowptr, esrc, ew, dis, bias, ln_g + (size_t)L * HID,
        ln_b + (size_t)L * HID, hbufs[L & 1]);
  }
  bf16_t* hfin = hbufs[1];

  int nchunks = N_EDGES / CE;
  for (int c = 0; c < nchunks; ++c) {
    int e0 = c * CE;
    const int* srcI = ei + e0;
    const int* dstI = ei + N_EDGES + e0;
    dim3 g1(1024 / BN, CE / BM);
    k_gemm<<<g1, 256, 0, stream>>>(nullptr, hfin, srcI, dstI, mw0t, mb0,
                                   z0, CE, 1024, 1024, 1);
    k_ln_relu_1024<<<CE / 4, 256, 0, stream>>>(z0, mg0, mbt0, CE);
    dim3 g2(HID / BN, CE / BM);
    k_gemm<<<g2, 256, 0, stream>>>(z0, nullptr, nullptr, nullptr, mw1t, mb1,
                                   z1, CE, HID, 1024, 0);
    k_ln_dot<<<CE / 4, 256, 0, stream>>>(z1, mg1, mbt1, mw2, mb2, out + e0, CE);
  }
  (void)in_sizes; (void)n_in; (void)out_size;
}

// Round 6
// 956.154 us; speedup vs baseline: 1.5142x; 1.5142x over previous
//
#include <hip/hip_runtime.h>
#include <hip/hip_bf16.h>
#include <stdint.h>

typedef __bf16 bf16_t;
typedef bf16_t bf16x8 __attribute__((ext_vector_type(8)));
typedef float f32x4 __attribute__((ext_vector_type(4)));

#define N_NODES 10000
#define N_EDGES 160000
#define IN_DIM 128
#define HID 512
#define LN_EPS 1e-5f

#define AS1 __attribute__((address_space(1)))
#define AS3 __attribute__((address_space(3)))

static __device__ __forceinline__ void gload_lds16(const void* g, void* l) {
  __builtin_amdgcn_global_load_lds((const AS1 void*)g, (AS3 void*)l, 16, 0, 0);
}

// ---------------- small utility kernels ----------------

__global__ void k_cast(const float* __restrict__ s, bf16_t* __restrict__ d, int n) {
  int i = blockIdx.x * 256 + threadIdx.x;
  if (i < n) d[i] = (bf16_t)s[i];
}

// LDS-tiled transpose+cast: dst[N][K] = bf16(src[K][N]); grid (N/32, K/32), 256 thr
__global__ __launch_bounds__(256) void k_tpose(const float* __restrict__ src,
                                               bf16_t* __restrict__ dst, int K, int N) {
  __shared__ float t[32][33];
  int cx = threadIdx.x & 31, ry = threadIdx.x >> 5;  // 0..31, 0..7
  int n0 = blockIdx.x * 32, k0 = blockIdx.y * 32;
#pragma unroll
  for (int i = 0; i < 32; i += 8)
    t[ry + i][cx] = src[(size_t)(k0 + ry + i) * N + n0 + cx];
  __syncthreads();
#pragma unroll
  for (int i = 0; i < 32; i += 8)
    dst[(size_t)(n0 + ry + i) * K + k0 + cx] = (bf16_t)t[cx][ry + i];
}

__global__ void k_deg_init(float* deg) {
  int i = blockIdx.x * 256 + threadIdx.x;
  if (i < N_NODES) deg[i] = 1.0f;  // self-loop
}
__global__ void k_deg_count(const int* __restrict__ col, float* deg) {
  int e = blockIdx.x * 256 + threadIdx.x;
  if (e < N_EDGES) atomicAdd(&deg[col[e]], 1.0f);
}
__global__ void k_dis(const float* __restrict__ deg, float* __restrict__ dis) {
  int i = blockIdx.x * 256 + threadIdx.x;
  if (i < N_NODES) dis[i] = rsqrtf(deg[i]);  // deg >= 1 always
}

// ---------------- CSR build (edges sorted by target) ----------------

__global__ void k_zero2(int* a, int* b) {
  int i = blockIdx.x * 256 + threadIdx.x;
  if (i < N_NODES) { a[i] = 0; b[i] = 0; }
}
__global__ void k_cnt(const int* __restrict__ col, int* cnt) {
  int e = blockIdx.x * 256 + threadIdx.x;
  if (e < N_EDGES) atomicAdd(&cnt[col[e]], 1);
}
// single-block exclusive scan: rowptr[0..N_NODES]
__global__ __launch_bounds__(256) void k_scan(const int* __restrict__ cnt,
                                              int* __restrict__ rowptr) {
  __shared__ int part[256];
  __shared__ int pref[257];
  int tid = threadIdx.x;
  const int CH = 40;  // 256*40 >= 10001
  int s = 0;
  for (int i = 0; i < CH; ++i) {
    int idx = tid * CH + i;
    if (idx < N_NODES) s += cnt[idx];
  }
  part[tid] = s;
  __syncthreads();
  if (tid == 0) {
    int a = 0;
    for (int i = 0; i < 256; ++i) { pref[i] = a; a += part[i]; }
    pref[256] = a;
  }
  __syncthreads();
  int a = pref[tid];
  for (int i = 0; i < CH; ++i) {
    int idx = tid * CH + i;
    if (idx < N_NODES) {
      rowptr[idx] = a;
      a += cnt[idx];
    } else if (idx == N_NODES) {
      rowptr[idx] = a;
    }
  }
}
__global__ void k_fill(const int* __restrict__ ei, const float* __restrict__ dis,
                       const int* __restrict__ rowptr, int* __restrict__ cursor,
                       int* __restrict__ esrc, float* __restrict__ ew) {
  int e = blockIdx.x * 256 + threadIdx.x;
  if (e >= N_EDGES) return;
  int s = ei[e];
  int t = ei[N_EDGES + e];
  int pos = atomicAdd(&cursor[t], 1);
  int o = rowptr[t] + pos;
  esrc[o] = s;
  ew[o] = dis[s] * dis[t];
}

// ---------------- fused aggregation + ReLU + LayerNorm (T in bf16) ----------------
__global__ __launch_bounds__(256) void k_agg_ln(
    const bf16_t* __restrict__ T, const int* __restrict__ rowptr,
    const int* __restrict__ esrc, const float* __restrict__ ew,
    const float* __restrict__ dis, const float* __restrict__ bias,
    const float* __restrict__ g, const float* __restrict__ b,
    bf16_t* __restrict__ out) {
  int w = threadIdx.x >> 6, lane = threadIdx.x & 63;
  int node = blockIdx.x * 4 + w;
  if (node >= N_NODES) return;
  int d0 = lane << 3;  // 8 dims per lane
  float dw = dis[node];
  dw *= dw;
  float a[8];
  {
    bf16x8 tn = *(const bf16x8*)(T + (size_t)node * HID + d0);
    const f32x4* bi = (const f32x4*)(bias + d0);
    f32x4 bv0 = bi[0], bv1 = bi[1];
#pragma unroll
    for (int j = 0; j < 4; ++j) a[j] = dw * (float)tn[j] + bv0[j];
#pragma unroll
    for (int j = 0; j < 4; ++j) a[4 + j] = dw * (float)tn[4 + j] + bv1[j];
  }
  int e = rowptr[node], e1 = rowptr[node + 1];
  for (; e + 1 < e1; e += 2) {
    int s0 = esrc[e], s1i = esrc[e + 1];
    float w0 = ew[e], w1 = ew[e + 1];
    bf16x8 t0 = *(const bf16x8*)(T + (size_t)s0 * HID + d0);
    bf16x8 t1 = *(const bf16x8*)(T + (size_t)s1i * HID + d0);
#pragma unroll
    for (int j = 0; j < 8; ++j) a[j] += w0 * (float)t0[j] + w1 * (float)t1[j];
  }
  if (e < e1) {
    int s0 = esrc[e];
    float w0 = ew[e];
    bf16x8 t0 = *(const bf16x8*)(T + (size_t)s0 * HID + d0);
#pragma unroll
    for (int j = 0; j < 8; ++j) a[j] += w0 * (float)t0[j];
  }
  float s1 = 0.f, s2 = 0.f;
#pragma unroll
  for (int j = 0; j < 8; ++j) {
    a[j] = fmaxf(a[j], 0.f);
    s1 += a[j];
    s2 += a[j] * a[j];
  }
#pragma unroll
  for (int off = 32; off > 0; off >>= 1) {
    s1 += __shfl_xor(s1, off);
    s2 += __shfl_xor(s2, off);
  }
  const float invD = 1.0f / (float)HID;
  float mean = s1 * invD;
  float var = s2 * invD - mean * mean;
  float inv = rsqrtf(var + LN_EPS);
  bf16_t ob[8];
#pragma unroll
  for (int j = 0; j < 8; ++j) {
    int d = d0 + j;
    ob[j] = (bf16_t)((a[j] - mean) * inv * g[d] + b[d]);
  }
  *(bf16x8*)(out + (size_t)node * HID + d0) = *(bf16x8*)ob;
}

// ---------------- per-edge: z0 = relu(LN(UV[src][0:1024] + UV[dst][1024:2048] + mb0))
// wave per edge, 16 elems/lane. UV bf16 [node][2048].
__global__ __launch_bounds__(256) void k_uv_ln(
    const bf16_t* __restrict__ UV, const int* __restrict__ srcI,
    const int* __restrict__ dstI, const float* __restrict__ mb0,
    const float* __restrict__ g, const float* __restrict__ b,
    bf16_t* __restrict__ z0, int rows) {
  int w = threadIdx.x >> 6, lane = threadIdx.x & 63;
  int row = blockIdx.x * 4 + w;
  if (row >= rows) return;
  int s = srcI[row], t = dstI[row];
  int d0 = lane << 4;  // 16 dims per lane
  const bf16_t* up = UV + (size_t)s * 2048 + d0;
  const bf16_t* vp = UV + (size_t)t * 2048 + 1024 + d0;
  bf16x8 u0 = *(const bf16x8*)up;
  bf16x8 u1 = *(const bf16x8*)(up + 8);
  bf16x8 v0 = *(const bf16x8*)vp;
  bf16x8 v1 = *(const bf16x8*)(vp + 8);
  float f[16];
#pragma unroll
  for (int j = 0; j < 8; ++j) {
    f[j] = (float)u0[j] + (float)v0[j] + mb0[d0 + j];
    f[8 + j] = (float)u1[j] + (float)v1[j] + mb0[d0 + 8 + j];
  }
  float s1 = 0.f, s2 = 0.f;
#pragma unroll
  for (int j = 0; j < 16; ++j) { s1 += f[j]; s2 += f[j] * f[j]; }
#pragma unroll
  for (int off = 32; off > 0; off >>= 1) {
    s1 += __shfl_xor(s1, off);
    s2 += __shfl_xor(s2, off);
  }
  const float invD = 1.0f / 1024.0f;
  float mean = s1 * invD;
  float var = s2 * invD - mean * mean;
  float inv = rsqrtf(var + LN_EPS);
  bf16_t o0[8], o1[8];
#pragma unroll
  for (int j = 0; j < 8; ++j) {
    o0[j] = (bf16_t)fmaxf((f[j] - mean) * inv * g[d0 + j] + b[d0 + j], 0.f);
    o1[j] = (bf16_t)fmaxf((f[8 + j] - mean) * inv * g[d0 + 8 + j] + b[d0 + 8 + j], 0.f);
  }
  bf16_t* zp = z0 + (size_t)row * 1024 + d0;
  *(bf16x8*)zp = *(bf16x8*)o0;
  *(bf16x8*)(zp + 8) = *(bf16x8*)o1;
}

// wave-per-row: out[row] = dot(relu(LN(z1[row])), mw2) + mb2, D=512, bf16 in
__global__ __launch_bounds__(256) void k_ln_dot(
    const bf16_t* __restrict__ z1, const float* __restrict__ g,
    const float* __restrict__ b, const float* __restrict__ mw2,
    const float* __restrict__ mb2, float* __restrict__ out, int rows) {
  int w = threadIdx.x >> 6, lane = threadIdx.x & 63;
  int row = blockIdx.x * 4 + w;
  if (row >= rows) return;
  int d0 = lane << 3;
  bf16x8 v = *(const bf16x8*)(z1 + (size_t)row * 512 + d0);
  float f[8];
#pragma unroll
  for (int j = 0; j < 8; ++j) f[j] = (float)v[j];
  float s1 = 0.f, s2 = 0.f;
#pragma unroll
  for (int j = 0; j < 8; ++j) { s1 += f[j]; s2 += f[j] * f[j]; }
#pragma unroll
  for (int off = 32; off > 0; off >>= 1) {
    s1 += __shfl_xor(s1, off);
    s2 += __shfl_xor(s2, off);
  }
  const float invD = 1.0f / 512.0f;
  float mean = s1 * invD;
  float var = s2 * invD - mean * mean;
  float inv = rsqrtf(var + LN_EPS);
  float acc = 0.f;
#pragma unroll
  for (int j = 0; j < 8; ++j) {
    float y = fmaxf((f[j] - mean) * inv * g[d0 + j] + b[d0 + j], 0.f);
    acc += y * mw2[d0 + j];
  }
#pragma unroll
  for (int off = 32; off > 0; off >>= 1) acc += __shfl_xor(acc, off);
  if (lane == 0) out[row] = acc + mb2[0];
}

// ---------------- streaming GEMM (m97 + chunk swizzle + LDS dbuf) ----------------
// C[M x N] = bf16(A[M x K] @ Bt^T + bias), Bt: [N x K] bf16.
#define BM 128
#define BN 128
#define BK 32

__global__ __launch_bounds__(256) void k_gemm(
    const bf16_t* __restrict__ A, const bf16_t* __restrict__ Bt,
    const float* __restrict__ bias, bf16_t* __restrict__ C,
    int M, int N, int K) {
  __shared__ __align__(16) bf16_t sA[2 * BM * BK];
  __shared__ __align__(16) bf16_t sB[2 * BN * BK];

  int tid = threadIdx.x;
  int row0 = blockIdx.y * BM, col0 = blockIdx.x * BN;
  int lane = tid & 63, w = tid >> 6;
  int quad = lane >> 4, l15 = lane & 15;
  int wr = (w >> 1) << 6, wc = (w & 1) << 6;

  int r0l = tid >> 2, r1l = r0l + 64;            // tile rows staged by this thread
  int kchunk = ((tid & 3) - (tid >> 3)) & 3;     // rotated global k-chunk
  int ksegg = kchunk << 3;

  int g0 = row0 + r0l; if (g0 >= M) g0 = M - 1;  // clamp; never stored
  int g1 = row0 + r1l; if (g1 >= M) g1 = M - 1;
  const bf16_t* pa0 = A + (size_t)g0 * K;
  const bf16_t* pa1 = A + (size_t)g1 * K;
  const bf16_t* pb0 = Bt + (size_t)(col0 + r0l) * K;
  const bf16_t* pb1 = Bt + (size_t)(col0 + r1l) * K;

  int ldsb = (tid & ~63) * 8;  // wave-uniform LDS element base

  auto stage = [&](int k0, int bsel) {
    int kk = k0 + ksegg;
    bf16_t* dA = sA + (bsel << 12) + ldsb;
    bf16_t* dB = sB + (bsel << 12) + ldsb;
    gload_lds16(pa0 + kk, dA);
    gload_lds16(pa1 + kk, dA + 2048);
    gload_lds16(pb0 + kk, dB);
    gload_lds16(pb1 + kk, dB + 2048);
  };

  f32x4 acc[4][4] = {};

  stage(0, 0);
  int buf = 0;
  for (int k0 = 0; k0 < K; k0 += BK) {
    __syncthreads();
    if (k0 + BK < K) stage(k0 + BK, buf ^ 1);

    int bo = buf << 12;
    bf16x8 af[4], bfr[4];
#pragma unroll
    for (int i = 0; i < 4; ++i) {
      int rr = wr + (i << 4) + l15;
      af[i] = *(const bf16x8*)&sA[bo + rr * BK + ((((quad + (rr >> 1)) & 3)) << 3)];
    }
#pragma unroll
    for (int j = 0; j < 4; ++j) {
      int rr = wc + (j << 4) + l15;
      bfr[j] = *(const bf16x8*)&sB[bo + rr * BK + ((((quad + (rr >> 1)) & 3)) << 3)];
    }
#pragma unroll
    for (int i = 0; i < 4; ++i)
#pragma unroll
      for (int j = 0; j < 4; ++j)
        acc[i][j] = __builtin_amdgcn_mfma_f32_16x16x32_bf16(af[i], bfr[j], acc[i][j], 0, 0, 0);
    buf ^= 1;
  }

  // epilogue: C/D layout col=lane&15, row=quad*4+reg (verified m89/m91)
#pragma unroll
  for (int i = 0; i < 4; ++i) {
    int r0e = row0 + wr + (i << 4) + (quad << 2);
#pragma unroll
    for (int j = 0; j < 4; ++j) {
      int gc = col0 + wc + (j << 4) + l15;
      float bb = bias ? bias[gc] : 0.0f;
#pragma unroll
      for (int r2 = 0; r2 < 4; ++r2) {
        int gr = r0e + r2;
        if (gr < M) C[(size_t)gr * N + gc] = (bf16_t)(acc[i][j][r2] + bb);
      }
    }
  }
}

// ---------------- host launch ----------------

extern "C" void kernel_launch(void* const* d_in, const int* in_sizes, int n_in,
                              void* d_out, int out_size, void* d_ws, size_t ws_size,
                              hipStream_t stream) {
  const float* x = (const float*)d_in[0];
  const int* ei = (const int*)d_in[1];
  const float* w0 = (const float*)d_in[2];
  const float* b0 = (const float*)d_in[3];
  const float* wsL = (const float*)d_in[4];
  const float* bsL = (const float*)d_in[5];
  const float* ln_g = (const float*)d_in[6];
  const float* ln_b = (const float*)d_in[7];
  const float* mw0 = (const float*)d_in[8];
  const float* mb0 = (const float*)d_in[9];
  const float* mg0 = (const float*)d_in[10];
  const float* mbt0 = (const float*)d_in[11];
  const float* mw1 = (const float*)d_in[12];
  const float* mb1 = (const float*)d_in[13];
  const float* mg1 = (const float*)d_in[14];
  const float* mbt1 = (const float*)d_in[15];
  const float* mw2 = (const float*)d_in[16];
  const float* mb2 = (const float*)d_in[17];
  float* out = (float*)d_out;

  char* p = (char*)d_ws;
  auto alloc = [&](size_t bytes) -> void* {
    void* r = (void*)p;
    p += (bytes + 255) & ~(size_t)255;
    return r;
  };
  float* deg = (float*)alloc((size_t)N_NODES * 4);
  float* dis = (float*)alloc((size_t)N_NODES * 4);
  int* cnt = (int*)alloc((size_t)N_NODES * 4);
  int* cursor = (int*)alloc((size_t)N_NODES * 4);
  int* rowptr = (int*)alloc((size_t)(N_NODES + 1) * 4);
  int* esrc = (int*)alloc((size_t)N_EDGES * 4);
  float* ew = (float*)alloc((size_t)N_EDGES * 4);
  bf16_t* xb = (bf16_t*)alloc((size_t)N_NODES * IN_DIM * 2);
  bf16_t* hb0 = (bf16_t*)alloc((size_t)N_NODES * HID * 2);
  bf16_t* hb1 = (bf16_t*)alloc((size_t)N_NODES * HID * 2);
  bf16_t* w0t = (bf16_t*)alloc((size_t)HID * IN_DIM * 2);
  bf16_t* wst = (bf16_t*)alloc((size_t)3 * HID * HID * 2);
  bf16_t* mw0t = (bf16_t*)alloc((size_t)2048 * 512 * 2);  // [W0_top | W0_bot] as Bt
  bf16_t* mw1t = (bf16_t*)alloc((size_t)512 * 1024 * 2);
  bf16_t* UV = (bf16_t*)alloc((size_t)N_NODES * 2048 * 2);  // h @ [top|bot], 41 MB
  size_t fixed = (size_t)(p - (char*)d_ws);

  // overlap pool: GCN-phase T (bf16, 10.24 MB) vs MLP z0 (2048 B/edge) + z1 (1024 B/edge)
  int CE = 4000;
  const int ce_opts[3] = {32000, 16000, 8000};
  for (int i = 0; i < 3; ++i) {
    size_t pool_need = (size_t)ce_opts[i] * 3072;
    size_t tneed = (size_t)N_NODES * HID * 2;
    if (pool_need < tneed) pool_need = tneed;
    if (fixed + pool_need + 4096 <= ws_size) { CE = ce_opts[i]; break; }
  }
  char* pool = p;
  bf16_t* T = (bf16_t*)pool;
  bf16_t* z0 = (bf16_t*)pool;  // aliases T; GCN fully precedes MLP (same stream)
  bf16_t* z1 = (bf16_t*)(pool + (size_t)CE * 2048);

  k_cast<<<(N_NODES * IN_DIM + 255) / 256, 256, 0, stream>>>(x, xb, N_NODES * IN_DIM);
  { dim3 g(HID / 32, IN_DIM / 32);
    k_tpose<<<g, 256, 0, stream>>>(w0, w0t, IN_DIM, HID); }
  for (int i = 0; i < 3; ++i) {
    dim3 g(HID / 32, HID / 32);
    k_tpose<<<g, 256, 0, stream>>>(wsL + (size_t)i * HID * HID,
                                   wst + (size_t)i * HID * HID, HID, HID);
  }
  // mw0 is [1024][1024] row-major: rows 0..511 = W0_top, rows 512..1023 = W0_bot.
  { dim3 g(1024 / 32, 512 / 32);
    k_tpose<<<g, 256, 0, stream>>>(mw0, mw0t, 512, 1024);                       // top
    k_tpose<<<g, 256, 0, stream>>>(mw0 + (size_t)512 * 1024,
                                   mw0t + (size_t)1024 * 512, 512, 1024); }     // bot
  { dim3 g(512 / 32, 1024 / 32);
    k_tpose<<<g, 256, 0, stream>>>(mw1, mw1t, 1024, 512); }

  k_deg_init<<<(N_NODES + 255) / 256, 256, 0, stream>>>(deg);
  k_deg_count<<<(N_EDGES + 255) / 256, 256, 0, stream>>>(ei + N_EDGES, deg);
  k_dis<<<(N_NODES + 255) / 256, 256, 0, stream>>>(deg, dis);

  k_zero2<<<(N_NODES + 255) / 256, 256, 0, stream>>>(cnt, cursor);
  k_cnt<<<(N_EDGES + 255) / 256, 256, 0, stream>>>(ei + N_EDGES, cnt);
  k_scan<<<1, 256, 0, stream>>>(cnt, rowptr);
  k_fill<<<(N_EDGES + 255) / 256, 256, 0, stream>>>(ei, dis, rowptr, cursor, esrc, ew);

  // ---- 4 GCN layers ----
  bf16_t* hbufs[2] = {hb0, hb1};
  for (int L = 0; L < 4; ++L) {
    const bf16_t* Ain = (L == 0) ? xb : hbufs[(L + 1) & 1];
    int K = (L == 0) ? IN_DIM : HID;
    const bf16_t* Bt = (L == 0) ? w0t : wst + (size_t)(L - 1) * HID * HID;
    dim3 grid(HID / BN, (N_NODES + BM - 1) / BM);
    k_gemm<<<grid, 256, 0, stream>>>(Ain, Bt, nullptr, T, N_NODES, HID, K);
    const float* bias = (L == 0) ? b0 : bsL + (size_t)(L - 1) * HID;
    k_agg_ln<<<(N_NODES + 3) / 4, 256, 0, stream>>>(
        T, rowptr, esrc, ew, dis, bias, ln_g + (size_t)L * HID,
        ln_b + (size_t)L * HID, hbufs[L & 1]);
  }
  bf16_t* hfin = hbufs[1];

  // ---- node-level UV = hfin @ [W0_top | W0_bot]  (10000 x 2048, K=512) ----
  { dim3 g(2048 / BN, (N_NODES + BM - 1) / BM);
    k_gemm<<<g, 256, 0, stream>>>(hfin, mw0t, nullptr, UV, N_NODES, 2048, 512); }

  // ---- edge MLP, chunked ----
  int nchunks = N_EDGES / CE;
  for (int c = 0; c < nchunks; ++c) {
    int e0 = c * CE;
    const int* srcI = ei + e0;
    const int* dstI = ei + N_EDGES + e0;
    k_uv_ln<<<CE / 4, 256, 0, stream>>>(UV, srcI, dstI, mb0, mg0, mbt0, z0, CE);
    dim3 g2(HID / BN, CE / BM);
    k_gemm<<<g2, 256, 0, stream>>>(z0, mw1t, mb1, z1, CE, HID, 1024);
    k_ln_dot<<<CE / 4, 256, 0, stream>>>(z1, mg1, mbt1, mw2, mb2, out + e0, CE);
  }
  (void)in_sizes; (void)n_in; (void)out_size;
}

// Round 7
// 944.508 us; speedup vs baseline: 1.5329x; 1.0123x over previous
//
#include <hip/hip_runtime.h>
#include <hip/hip_bf16.h>
#include <stdint.h>

typedef __bf16 bf16_t;
typedef bf16_t bf16x8 __attribute__((ext_vector_type(8)));
typedef float f32x4 __attribute__((ext_vector_type(4)));

#define N_NODES 10000
#define N_EDGES 160000
#define IN_DIM 128
#define HID 512
#define LN_EPS 1e-5f
#define BK 32

#define AS1 __attribute__((address_space(1)))
#define AS3 __attribute__((address_space(3)))

static __device__ __forceinline__ void gload_lds16(const void* g, void* l) {
  __builtin_amdgcn_global_load_lds((const AS1 void*)g, (AS3 void*)l, 16, 0, 0);
}

// ---------------- small utility kernels ----------------

__global__ void k_cast(const float* __restrict__ s, bf16_t* __restrict__ d, int n) {
  int i = blockIdx.x * 256 + threadIdx.x;
  if (i < n) d[i] = (bf16_t)s[i];
}

// LDS-tiled transpose+cast: dst[N][K] = bf16(src[K][N]); grid (N/32, K/32), 256 thr
__global__ __launch_bounds__(256) void k_tpose(const float* __restrict__ src,
                                               bf16_t* __restrict__ dst, int K, int N) {
  __shared__ float t[32][33];
  int cx = threadIdx.x & 31, ry = threadIdx.x >> 5;  // 0..31, 0..7
  int n0 = blockIdx.x * 32, k0 = blockIdx.y * 32;
#pragma unroll
  for (int i = 0; i < 32; i += 8)
    t[ry + i][cx] = src[(size_t)(k0 + ry + i) * N + n0 + cx];
  __syncthreads();
#pragma unroll
  for (int i = 0; i < 32; i += 8)
    dst[(size_t)(n0 + ry + i) * K + k0 + cx] = (bf16_t)t[cx][ry + i];
}

__global__ void k_deg_init(float* deg) {
  int i = blockIdx.x * 256 + threadIdx.x;
  if (i < N_NODES) deg[i] = 1.0f;  // self-loop
}
__global__ void k_deg_count(const int* __restrict__ col, float* deg) {
  int e = blockIdx.x * 256 + threadIdx.x;
  if (e < N_EDGES) atomicAdd(&deg[col[e]], 1.0f);
}
__global__ void k_dis(const float* __restrict__ deg, float* __restrict__ dis) {
  int i = blockIdx.x * 256 + threadIdx.x;
  if (i < N_NODES) dis[i] = rsqrtf(deg[i]);  // deg >= 1 always
}

// ---------------- CSR build (edges sorted by target) ----------------

__global__ void k_zero2(int* a, int* b) {
  int i = blockIdx.x * 256 + threadIdx.x;
  if (i < N_NODES) { a[i] = 0; b[i] = 0; }
}
__global__ void k_cnt(const int* __restrict__ col, int* cnt) {
  int e = blockIdx.x * 256 + threadIdx.x;
  if (e < N_EDGES) atomicAdd(&cnt[col[e]], 1);
}
// single-block exclusive scan: rowptr[0..N_NODES]
__global__ __launch_bounds__(256) void k_scan(const int* __restrict__ cnt,
                                              int* __restrict__ rowptr) {
  __shared__ int part[256];
  __shared__ int pref[257];
  int tid = threadIdx.x;
  const int CH = 40;  // 256*40 >= 10001
  int s = 0;
  for (int i = 0; i < CH; ++i) {
    int idx = tid * CH + i;
    if (idx < N_NODES) s += cnt[idx];
  }
  part[tid] = s;
  __syncthreads();
  if (tid == 0) {
    int a = 0;
    for (int i = 0; i < 256; ++i) { pref[i] = a; a += part[i]; }
    pref[256] = a;
  }
  __syncthreads();
  int a = pref[tid];
  for (int i = 0; i < CH; ++i) {
    int idx = tid * CH + i;
    if (idx < N_NODES) {
      rowptr[idx] = a;
      a += cnt[idx];
    } else if (idx == N_NODES) {
      rowptr[idx] = a;
    }
  }
}
__global__ void k_fill(const int* __restrict__ ei, const float* __restrict__ dis,
                       const int* __restrict__ rowptr, int* __restrict__ cursor,
                       int* __restrict__ esrc, float* __restrict__ ew) {
  int e = blockIdx.x * 256 + threadIdx.x;
  if (e >= N_EDGES) return;
  int s = ei[e];
  int t = ei[N_EDGES + e];
  int pos = atomicAdd(&cursor[t], 1);
  int o = rowptr[t] + pos;
  esrc[o] = s;
  ew[o] = dis[s] * dis[t];
}

// ---------------- fused aggregation + ReLU + LayerNorm (T in bf16) ----------------
__global__ __launch_bounds__(256) void k_agg_ln(
    const bf16_t* __restrict__ T, const int* __restrict__ rowptr,
    const int* __restrict__ esrc, const float* __restrict__ ew,
    const float* __restrict__ dis, const float* __restrict__ bias,
    const float* __restrict__ g, const float* __restrict__ b,
    bf16_t* __restrict__ out) {
  int w = threadIdx.x >> 6, lane = threadIdx.x & 63;
  int node = blockIdx.x * 4 + w;
  if (node >= N_NODES) return;
  int d0 = lane << 3;  // 8 dims per lane
  float dw = dis[node];
  dw *= dw;
  float a[8];
  {
    bf16x8 tn = *(const bf16x8*)(T + (size_t)node * HID + d0);
    const f32x4* bi = (const f32x4*)(bias + d0);
    f32x4 bv0 = bi[0], bv1 = bi[1];
#pragma unroll
    for (int j = 0; j < 4; ++j) a[j] = dw * (float)tn[j] + bv0[j];
#pragma unroll
    for (int j = 0; j < 4; ++j) a[4 + j] = dw * (float)tn[4 + j] + bv1[j];
  }
  int e = rowptr[node], e1 = rowptr[node + 1];
  for (; e + 1 < e1; e += 2) {
    int s0 = esrc[e], s1i = esrc[e + 1];
    float w0 = ew[e], w1 = ew[e + 1];
    bf16x8 t0 = *(const bf16x8*)(T + (size_t)s0 * HID + d0);
    bf16x8 t1 = *(const bf16x8*)(T + (size_t)s1i * HID + d0);
#pragma unroll
    for (int j = 0; j < 8; ++j) a[j] += w0 * (float)t0[j] + w1 * (float)t1[j];
  }
  if (e < e1) {
    int s0 = esrc[e];
    float w0 = ew[e];
    bf16x8 t0 = *(const bf16x8*)(T + (size_t)s0 * HID + d0);
#pragma unroll
    for (int j = 0; j < 8; ++j) a[j] += w0 * (float)t0[j];
  }
  float s1 = 0.f, s2 = 0.f;
#pragma unroll
  for (int j = 0; j < 8; ++j) {
    a[j] = fmaxf(a[j], 0.f);
    s1 += a[j];
    s2 += a[j] * a[j];
  }
#pragma unroll
  for (int off = 32; off > 0; off >>= 1) {
    s1 += __shfl_xor(s1, off);
    s2 += __shfl_xor(s2, off);
  }
  const float invD = 1.0f / (float)HID;
  float mean = s1 * invD;
  float var = s2 * invD - mean * mean;
  float inv = rsqrtf(var + LN_EPS);
  bf16_t ob[8];
#pragma unroll
  for (int j = 0; j < 8; ++j) {
    int d = d0 + j;
    ob[j] = (bf16_t)((a[j] - mean) * inv * g[d] + b[d]);
  }
  *(bf16x8*)(out + (size_t)node * HID + d0) = *(bf16x8*)ob;
}

// ---------------- per-edge: z0 = relu(LN(UV[src][0:1024] + UV[dst][1024:2048] + mb0))
__global__ __launch_bounds__(256) void k_uv_ln(
    const bf16_t* __restrict__ UV, const int* __restrict__ srcI,
    const int* __restrict__ dstI, const float* __restrict__ mb0,
    const float* __restrict__ g, const float* __restrict__ b,
    bf16_t* __restrict__ z0, int rows) {
  int w = threadIdx.x >> 6, lane = threadIdx.x & 63;
  int row = blockIdx.x * 4 + w;
  if (row >= rows) return;
  int s = srcI[row], t = dstI[row];
  int d0 = lane << 4;  // 16 dims per lane
  const bf16_t* up = UV + (size_t)s * 2048 + d0;
  const bf16_t* vp = UV + (size_t)t * 2048 + 1024 + d0;
  bf16x8 u0 = *(const bf16x8*)up;
  bf16x8 u1 = *(const bf16x8*)(up + 8);
  bf16x8 v0 = *(const bf16x8*)vp;
  bf16x8 v1 = *(const bf16x8*)(vp + 8);
  float f[16];
#pragma unroll
  for (int j = 0; j < 8; ++j) {
    f[j] = (float)u0[j] + (float)v0[j] + mb0[d0 + j];
    f[8 + j] = (float)u1[j] + (float)v1[j] + mb0[d0 + 8 + j];
  }
  float s1 = 0.f, s2 = 0.f;
#pragma unroll
  for (int j = 0; j < 16; ++j) { s1 += f[j]; s2 += f[j] * f[j]; }
#pragma unroll
  for (int off = 32; off > 0; off >>= 1) {
    s1 += __shfl_xor(s1, off);
    s2 += __shfl_xor(s2, off);
  }
  const float invD = 1.0f / 1024.0f;
  float mean = s1 * invD;
  float var = s2 * invD - mean * mean;
  float inv = rsqrtf(var + LN_EPS);
  bf16_t o0[8], o1[8];
#pragma unroll
  for (int j = 0; j < 8; ++j) {
    o0[j] = (bf16_t)fmaxf((f[j] - mean) * inv * g[d0 + j] + b[d0 + j], 0.f);
    o1[j] = (bf16_t)fmaxf((f[8 + j] - mean) * inv * g[d0 + 8 + j] + b[d0 + 8 + j], 0.f);
  }
  bf16_t* zp = z0 + (size_t)row * 1024 + d0;
  *(bf16x8*)zp = *(bf16x8*)o0;
  *(bf16x8*)(zp + 8) = *(bf16x8*)o1;
}

// wave-per-row: out[row] = dot(relu(LN(z1[row])), mw2) + mb2, D=512, bf16 in
__global__ __launch_bounds__(256) void k_ln_dot(
    const bf16_t* __restrict__ z1, const float* __restrict__ g,
    const float* __restrict__ b, const float* __restrict__ mw2,
    const float* __restrict__ mb2, float* __restrict__ out, int rows) {
  int w = threadIdx.x >> 6, lane = threadIdx.x & 63;
  int row = blockIdx.x * 4 + w;
  if (row >= rows) return;
  int d0 = lane << 3;
  bf16x8 v = *(const bf16x8*)(z1 + (size_t)row * 512 + d0);
  float f[8];
#pragma unroll
  for (int j = 0; j < 8; ++j) f[j] = (float)v[j];
  float s1 = 0.f, s2 = 0.f;
#pragma unroll
  for (int j = 0; j < 8; ++j) { s1 += f[j]; s2 += f[j] * f[j]; }
#pragma unroll
  for (int off = 32; off > 0; off >>= 1) {
    s1 += __shfl_xor(s1, off);
    s2 += __shfl_xor(s2, off);
  }
  const float invD = 1.0f / 512.0f;
  float mean = s1 * invD;
  float var = s2 * invD - mean * mean;
  float inv = rsqrtf(var + LN_EPS);
  float acc = 0.f;
#pragma unroll
  for (int j = 0; j < 8; ++j) {
    float y = fmaxf((f[j] - mean) * inv * g[d0 + j] + b[d0 + j], 0.f);
    acc += y * mw2[d0 + j];
  }
#pragma unroll
  for (int off = 32; off > 0; off >>= 1) acc += __shfl_xor(acc, off);
  if (lane == 0) out[row] = acc + mb2[0];
}

// ---------------- streaming GEMM, templated tile, XCD-co-located grid ----------
// C[M x N] = bf16(A @ Bt^T + bias). Grid: x = row-blocks (padded to x8), y = cols.
// linear id ≡ blockIdx.x (mod 8) -> all col-tiles of a row-block share an XCD,
// so the A-tile is fetched once into that XCD's L2 and hit 3x.
template <int BMt, int BNt>
__global__ __launch_bounds__(256) void k_gemm(
    const bf16_t* __restrict__ A, const bf16_t* __restrict__ Bt,
    const float* __restrict__ bias, bf16_t* __restrict__ C,
    int M, int N, int K) {
  constexpr int RI = BMt / 32, CJ = BNt / 32;   // frags per wave
  constexpr int SA = BMt / 64, SB = BNt / 64;   // staging steps
  constexpr int EA = BMt * BK, EB = BNt * BK;   // elems per LDS buffer
  __shared__ __align__(16) bf16_t sA[2 * EA];
  __shared__ __align__(16) bf16_t sB[2 * EB];

  int tid = threadIdx.x;
  int row0 = blockIdx.x * BMt, col0 = blockIdx.y * BNt;
  if (row0 >= M) return;  // padded row-blocks
  int lane = tid & 63, w = tid >> 6;
  int quad = lane >> 4, l15 = lane & 15;
  int wr = (w >> 1) * (BMt / 2), wc = (w & 1) * (BNt / 2);

  int rbase = tid >> 2;                       // 0..63, row within staging step
  int kchunk = ((tid & 3) - (tid >> 3)) & 3;  // rotated global k-chunk (bank swizzle)
  int ksegg = kchunk << 3;

  const bf16_t* pa[SA];
  const bf16_t* pb[SB];
#pragma unroll
  for (int s = 0; s < SA; ++s) {
    int g0 = row0 + rbase + s * 64;
    if (g0 >= M) g0 = M - 1;  // clamp; never stored
    pa[s] = A + (size_t)g0 * K;
  }
#pragma unroll
  for (int s = 0; s < SB; ++s)
    pb[s] = Bt + (size_t)(col0 + rbase + s * 64) * K;

  int ldsb = (tid & ~63) * 8;  // wave-uniform LDS element base

  auto stage = [&](int k0, int bsel) {
    int kk = k0 + ksegg;
    bf16_t* dA = sA + bsel * EA + ldsb;
    bf16_t* dB = sB + bsel * EB + ldsb;
#pragma unroll
    for (int s = 0; s < SA; ++s) gload_lds16(pa[s] + kk, dA + s * 2048);
#pragma unroll
    for (int s = 0; s < SB; ++s) gload_lds16(pb[s] + kk, dB + s * 2048);
  };

  f32x4 acc[RI][CJ] = {};

  stage(0, 0);
  int buf = 0;
  for (int k0 = 0; k0 < K; k0 += BK) {
    __syncthreads();
    if (k0 + BK < K) stage(k0 + BK, buf ^ 1);

    int boA = buf * EA, boB = buf * EB;
    bf16x8 af[RI], bfr[CJ];
#pragma unroll
    for (int i = 0; i < RI; ++i) {
      int rr = wr + (i << 4) + l15;
      af[i] = *(const bf16x8*)&sA[boA + rr * BK + (((quad + (rr >> 1)) & 3) << 3)];
    }
#pragma unroll
    for (int j = 0; j < CJ; ++j) {
      int rr = wc + (j << 4) + l15;
      bfr[j] = *(const bf16x8*)&sB[boB + rr * BK + (((quad + (rr >> 1)) & 3) << 3)];
    }
#pragma unroll
    for (int i = 0; i < RI; ++i)
#pragma unroll
      for (int j = 0; j < CJ; ++j)
        acc[i][j] = __builtin_amdgcn_mfma_f32_16x16x32_bf16(af[i], bfr[j], acc[i][j], 0, 0, 0);
    buf ^= 1;
  }

  // epilogue: C/D layout col=lane&15, row=quad*4+reg (verified m89/m91)
#pragma unroll
  for (int i = 0; i < RI; ++i) {
    int r0e = row0 + wr + (i << 4) + (quad << 2);
#pragma unroll
    for (int j = 0; j < CJ; ++j) {
      int gc = col0 + wc + (j << 4) + l15;
      float bb = bias ? bias[gc] : 0.0f;
#pragma unroll
      for (int r2 = 0; r2 < 4; ++r2) {
        int gr = r0e + r2;
        if (gr < M) C[(size_t)gr * N + gc] = (bf16_t)(acc[i][j][r2] + bb);
      }
    }
  }
}

// ---------------- host launch ----------------

static inline int pad8(int x) { return (x + 7) & ~7; }

extern "C" void kernel_launch(void* const* d_in, const int* in_sizes, int n_in,
                              void* d_out, int out_size, void* d_ws, size_t ws_size,
                              hipStream_t stream) {
  const float* x = (const float*)d_in[0];
  const int* ei = (const int*)d_in[1];
  const float* w0 = (const float*)d_in[2];
  const float* b0 = (const float*)d_in[3];
  const float* wsL = (const float*)d_in[4];
  const float* bsL = (const float*)d_in[5];
  const float* ln_g = (const float*)d_in[6];
  const float* ln_b = (const float*)d_in[7];
  const float* mw0 = (const float*)d_in[8];
  const float* mb0 = (const float*)d_in[9];
  const float* mg0 = (const float*)d_in[10];
  const float* mbt0 = (const float*)d_in[11];
  const float* mw1 = (const float*)d_in[12];
  const float* mb1 = (const float*)d_in[13];
  const float* mg1 = (const float*)d_in[14];
  const float* mbt1 = (const float*)d_in[15];
  const float* mw2 = (const float*)d_in[16];
  const float* mb2 = (const float*)d_in[17];
  float* out = (float*)d_out;

  char* p = (char*)d_ws;
  auto alloc = [&](size_t bytes) -> void* {
    void* r = (void*)p;
    p += (bytes + 255) & ~(size_t)255;
    return r;
  };
  float* deg = (float*)alloc((size_t)N_NODES * 4);
  float* dis = (float*)alloc((size_t)N_NODES * 4);
  int* cnt = (int*)alloc((size_t)N_NODES * 4);
  int* cursor = (int*)alloc((size_t)N_NODES * 4);
  int* rowptr = (int*)alloc((size_t)(N_NODES + 1) * 4);
  int* esrc = (int*)alloc((size_t)N_EDGES * 4);
  float* ew = (float*)alloc((size_t)N_EDGES * 4);
  bf16_t* xb = (bf16_t*)alloc((size_t)N_NODES * IN_DIM * 2);
  bf16_t* hb0 = (bf16_t*)alloc((size_t)N_NODES * HID * 2);
  bf16_t* hb1 = (bf16_t*)alloc((size_t)N_NODES * HID * 2);
  bf16_t* w0t = (bf16_t*)alloc((size_t)HID * IN_DIM * 2);
  bf16_t* wst = (bf16_t*)alloc((size_t)3 * HID * HID * 2);
  bf16_t* mw0t = (bf16_t*)alloc((size_t)2048 * 512 * 2);  // [W0_top | W0_bot] as Bt
  bf16_t* mw1t = (bf16_t*)alloc((size_t)512 * 1024 * 2);
  bf16_t* UV = (bf16_t*)alloc((size_t)N_NODES * 2048 * 2);  // h @ [top|bot], 41 MB
  size_t fixed = (size_t)(p - (char*)d_ws);

  // overlap pool: GCN-phase T (bf16, 10.24 MB) vs MLP z0 (2048 B/edge) + z1 (1024 B/edge)
  // CE must be a multiple of 128 and divide 160000.
  int CE = 3200;
  const int ce_opts[3] = {32000, 16000, 6400};
  for (int i = 0; i < 3; ++i) {
    size_t pool_need = (size_t)ce_opts[i] * 3072;
    size_t tneed = (size_t)N_NODES * HID * 2;
    if (pool_need < tneed) pool_need = tneed;
    if (fixed + pool_need + 4096 <= ws_size) { CE = ce_opts[i]; break; }
  }
  char* pool = p;
  bf16_t* T = (bf16_t*)pool;
  bf16_t* z0 = (bf16_t*)pool;  // aliases T; GCN fully precedes MLP (same stream)
  bf16_t* z1 = (bf16_t*)(pool + (size_t)CE * 2048);

  k_cast<<<(N_NODES * IN_DIM + 255) / 256, 256, 0, stream>>>(x, xb, N_NODES * IN_DIM);
  { dim3 g(HID / 32, IN_DIM / 32);
    k_tpose<<<g, 256, 0, stream>>>(w0, w0t, IN_DIM, HID); }
  for (int i = 0; i < 3; ++i) {
    dim3 g(HID / 32, HID / 32);
    k_tpose<<<g, 256, 0, stream>>>(wsL + (size_t)i * HID * HID,
                                   wst + (size_t)i * HID * HID, HID, HID);
  }
  // mw0 is [1024][1024] row-major: rows 0..511 = W0_top, rows 512..1023 = W0_bot.
  { dim3 g(1024 / 32, 512 / 32);
    k_tpose<<<g, 256, 0, stream>>>(mw0, mw0t, 512, 1024);                       // top
    k_tpose<<<g, 256, 0, stream>>>(mw0 + (size_t)512 * 1024,
                                   mw0t + (size_t)1024 * 512, 512, 1024); }     // bot
  { dim3 g(512 / 32, 1024 / 32);
    k_tpose<<<g, 256, 0, stream>>>(mw1, mw1t, 1024, 512); }

  k_deg_init<<<(N_NODES + 255) / 256, 256, 0, stream>>>(deg);
  k_deg_count<<<(N_EDGES + 255) / 256, 256, 0, stream>>>(ei + N_EDGES, deg);
  k_dis<<<(N_NODES + 255) / 256, 256, 0, stream>>>(deg, dis);

  k_zero2<<<(N_NODES + 255) / 256, 256, 0, stream>>>(cnt, cursor);
  k_cnt<<<(N_EDGES + 255) / 256, 256, 0, stream>>>(ei + N_EDGES, cnt);
  k_scan<<<1, 256, 0, stream>>>(cnt, rowptr);
  k_fill<<<(N_EDGES + 255) / 256, 256, 0, stream>>>(ei, dis, rowptr, cursor, esrc, ew);

  // ---- 4 GCN layers (64x128 tile: 640 blocks -> 2.5 blocks/CU) ----
  int nrb64 = pad8((N_NODES + 63) / 64);  // 157 -> 160
  bf16_t* hbufs[2] = {hb0, hb1};
  for (int L = 0; L < 4; ++L) {
    const bf16_t* Ain = (L == 0) ? xb : hbufs[(L + 1) & 1];
    int K = (L == 0) ? IN_DIM : HID;
    const bf16_t* Bt = (L == 0) ? w0t : wst + (size_t)(L - 1) * HID * HID;
    dim3 grid(nrb64, HID / 128);
    k_gemm<64, 128><<<grid, 256, 0, stream>>>(Ain, Bt, nullptr, T, N_NODES, HID, K);
    const float* bias = (L == 0) ? b0 : bsL + (size_t)(L - 1) * HID;
    k_agg_ln<<<(N_NODES + 3) / 4, 256, 0, stream>>>(
        T, rowptr, esrc, ew, dis, bias, ln_g + (size_t)L * HID,
        ln_b + (size_t)L * HID, hbufs[L & 1]);
  }
  bf16_t* hfin = hbufs[1];

  // ---- node-level UV = hfin @ [W0_top | W0_bot]  (10000 x 2048, K=512) ----
  { dim3 g(nrb64, 2048 / 128);
    k_gemm<64, 128><<<g, 256, 0, stream>>>(hfin, mw0t, nullptr, UV, N_NODES, 2048, 512); }

  // ---- edge MLP, chunked ----
  int nchunks = N_EDGES / CE;
  for (int c = 0; c < nchunks; ++c) {
    int e0 = c * CE;
    const int* srcI = ei + e0;
    const int* dstI = ei + N_EDGES + e0;
    k_uv_ln<<<CE / 4, 256, 0, stream>>>(UV, srcI, dstI, mb0, mg0, mbt0, z0, CE);
    dim3 g2(pad8(CE / 128), HID / 128);
    k_gemm<128, 128><<<g2, 256, 0, stream>>>(z0, mw1t, mb1, z1, CE, HID, 1024);
    k_ln_dot<<<CE / 4, 256, 0, stream>>>(z1, mg1, mbt1, mw2, mb2, out + e0, CE);
  }
  (void)in_sizes; (void)n_in; (void)out_size;
}